// Round 5
// baseline (299.900 us; speedup 1.0000x reference)
//
#include <hip/hip_runtime.h>
#include <hip/hip_bf16.h>
#include <math.h>

typedef __attribute__((ext_vector_type(8))) short bf16x8;
typedef __attribute__((ext_vector_type(4))) float f32x4;
typedef __attribute__((ext_vector_type(4))) unsigned int u32x4;
typedef __attribute__((ext_vector_type(2))) unsigned int u32x2;

constexpr int NB = 16, NQ = 4096, LF = 2048, C = 256;

__device__ __forceinline__ unsigned short bfbits(float x) {
    return __builtin_bit_cast(unsigned short, __float2bfloat16(x));
}
__device__ __forceinline__ unsigned pk2(float a, float b) {
    return (unsigned)bfbits(a) | ((unsigned)bfbits(b) << 16);
}
__device__ __forceinline__ float bflo(unsigned d) { return __builtin_bit_cast(float, d << 16); }
__device__ __forceinline__ float bfhi(unsigned d) { return __builtin_bit_cast(float, d & 0xffff0000u); }

// ---- prep: weights -> bf16 fragment-linear layout in ws ----
// ws[off + f*8 + e] = w[nt*16 + (lane&15)][ks*32 + (lane>>4)*8 + e],  f = (nt*NKS+ks)*64 + lane
// offsets (ushort): w1c1=0, w1c2=16384, w2c1=32768, w2c2=49152, gw1=65536  (total 393216 B)
__global__ void prep_weights(const float* __restrict__ c1w1, const float* __restrict__ c2w1,
                             const float* __restrict__ c1w2, const float* __restrict__ c2w2,
                             const float* __restrict__ gw1, unsigned short* __restrict__ ws)
{
    int t = blockIdx.x * 256 + threadIdx.x;          // 0..24575
    const float* src; int K, nks, dstoff, f;
    if (t < 2048)      { src = c1w1; K = 256; nks = 8;  dstoff = 0;      f = t; }
    else if (t < 4096) { src = c2w1; K = 256; nks = 8;  dstoff = 16384;  f = t - 2048; }
    else if (t < 6144) { src = c1w2; K = 64;  nks = 2;  dstoff = 32768;  f = t - 4096; }
    else if (t < 8192) { src = c2w2; K = 64;  nks = 2;  dstoff = 49152;  f = t - 6144; }
    else               { src = gw1;  K = 512; nks = 16; dstoff = 65536;  f = t - 8192; }
    int l = f & 63, s = f >> 6;
    int nt = s / nks, ks = s % nks;
    int n  = nt * 16 + (l & 15);
    int k0 = ks * 32 + (l >> 4) * 8;
    unsigned short* d = ws + dstoff + (size_t)f * 8;
    const float* sp = src + (size_t)n * K + k0;
    #pragma unroll
    for (int e = 0; e < 8; ++e) d[e] = bfbits(sp[e]);
}

// ---- main: dual-tile (32 rows) waves, shared weight frags, aliased LDS, no barriers ----
__global__ __launch_bounds__(256, 2)
void semalign_v5(const float* __restrict__ feat,  const float* __restrict__ qbox,
                 const float* __restrict__ qfeat, const float* __restrict__ posf,
                 const float* __restrict__ c1b1,  const float* __restrict__ c1b2,
                 const float* __restrict__ c1g,   const float* __restrict__ c1be,
                 const float* __restrict__ c2b1,  const float* __restrict__ c2b2,
                 const float* __restrict__ c2g,   const float* __restrict__ c2be,
                 const float* __restrict__ gb1,   const float* __restrict__ gw2,
                 const float* __restrict__ gb2,
                 const unsigned short* __restrict__ wsb,
                 float* __restrict__ out)
{
    // 64 KiB: per (wave, tile) an 8 KiB region. Pooled transpose [16][256] bf16 lives
    // in the full region; the H transpose (sH[2][16][64], 4 KiB) aliases its head —
    // H is fully consumed into registers before pooled writes begin.
    __shared__ __align__(16) unsigned short sP[4][2][16][256];

    const int tid = threadIdx.x, l = tid & 63, wid = tid >> 6;
    const int lr = l & 15, lg = l >> 4;
    const int rowb = blockIdx.x * 128 + wid * 32;    // 32 rows per wave = 2 queries
    const int q0 = rowb >> 4;
    const int b = lr;
    const int swz = (lr & 7) << 4;

    const float *prow[2], *qrow[2], *srow[2], *erow[2];
    #pragma unroll
    for (int t = 0; t < 2; ++t) {
        int q = q0 + t;
        prow[t] = posf  + ((size_t)b * NQ + q) * C;
        qrow[t] = qfeat + ((size_t)b * NQ + q) * C;
        float cx = qbox[((size_t)b * NQ + q) * 2 + 0];
        float w  = qbox[((size_t)b * NQ + q) * 2 + 1];
        float fs = fminf(fmaxf((cx - 0.5f * w) * (float)LF, 0.f), (float)(LF - 1));
        float fe = fminf(fmaxf((cx + 0.5f * w) * (float)LF, 0.f), (float)(LF - 1));
        srow[t] = feat + ((size_t)b * LF + (int)rintf(fs)) * C;
        erow[t] = feat + ((size_t)b * LF + (int)rintf(fe)) * C;
    }

    // ---------- GEMM1: both contrasts, both tiles share each weight frag ----------
    f32x4 a1[2][4] = {}, a2[2][4] = {};
    #pragma unroll
    for (int ks = 0; ks < 8; ++ks) {
        int k0 = ks * 32 + lg * 8;
        bf16x8 v1f[2], v2f[2];
        #pragma unroll
        for (int t = 0; t < 2; ++t) {
            float4 s0 = *(const float4*)(srow[t] + k0), s1 = *(const float4*)(srow[t] + k0 + 4);
            float4 e0 = *(const float4*)(erow[t] + k0), e1 = *(const float4*)(erow[t] + k0 + 4);
            float4 p0 = *(const float4*)(prow[t] + k0), p1 = *(const float4*)(prow[t] + k0 + 4);
            u32x4 a, c;
            a[0] = pk2(s0.x * p0.x, s0.y * p0.y); a[1] = pk2(s0.z * p0.z, s0.w * p0.w);
            a[2] = pk2(s1.x * p1.x, s1.y * p1.y); a[3] = pk2(s1.z * p1.z, s1.w * p1.w);
            c[0] = pk2(e0.x * p0.x, e0.y * p0.y); c[1] = pk2(e0.z * p0.z, e0.w * p0.w);
            c[2] = pk2(e1.x * p1.x, e1.y * p1.y); c[3] = pk2(e1.z * p1.z, e1.w * p1.w);
            v1f[t] = __builtin_bit_cast(bf16x8, a);
            v2f[t] = __builtin_bit_cast(bf16x8, c);
        }
        #pragma unroll
        for (int nt = 0; nt < 4; ++nt) {
            bf16x8 wA = *(const bf16x8*)(wsb + ((size_t)((nt * 8 + ks) * 64 + l)) * 8);
            bf16x8 wB = *(const bf16x8*)(wsb + 16384 + ((size_t)((nt * 8 + ks) * 64 + l)) * 8);
            a1[0][nt] = __builtin_amdgcn_mfma_f32_16x16x32_bf16(wA, v1f[0], a1[0][nt], 0, 0, 0);
            a1[1][nt] = __builtin_amdgcn_mfma_f32_16x16x32_bf16(wA, v1f[1], a1[1][nt], 0, 0, 0);
            a2[0][nt] = __builtin_amdgcn_mfma_f32_16x16x32_bf16(wB, v2f[0], a2[0][nt], 0, 0, 0);
            a2[1][nt] = __builtin_amdgcn_mfma_f32_16x16x32_bf16(wB, v2f[1], a2[1][nt], 0, 0, 0);
        }
    }
    // bias + relu + pack -> sH (head of each tile's sP region)
    #pragma unroll
    for (int nt = 0; nt < 4; ++nt) {
        float4 b1v = *(const float4*)(c1b1 + nt * 16 + lg * 4);
        float4 b2v = *(const float4*)(c2b1 + nt * 16 + lg * 4);
        #pragma unroll
        for (int t = 0; t < 2; ++t) {
            char* hb = (char*)&sP[wid][t][0][0];
            u32x2 wv;
            wv[0] = pk2(fmaxf(a1[t][nt][0] + b1v.x, 0.f), fmaxf(a1[t][nt][1] + b1v.y, 0.f));
            wv[1] = pk2(fmaxf(a1[t][nt][2] + b1v.z, 0.f), fmaxf(a1[t][nt][3] + b1v.w, 0.f));
            *(u32x2*)(hb + lr * 128 + ((nt * 32 + lg * 8) ^ swz)) = wv;
            wv[0] = pk2(fmaxf(a2[t][nt][0] + b2v.x, 0.f), fmaxf(a2[t][nt][1] + b2v.y, 0.f));
            wv[1] = pk2(fmaxf(a2[t][nt][2] + b2v.z, 0.f), fmaxf(a2[t][nt][3] + b2v.w, 0.f));
            *(u32x2*)(hb + 2048 + lr * 128 + ((nt * 32 + lg * 8) ^ swz)) = wv;
        }
    }
    asm volatile("s_waitcnt lgkmcnt(0)" ::: "memory");

    // ---------- GEMM2 + LN + sigmoid + pooled, per tile (both contrasts together) ----------
    #pragma unroll
    for (int t = 0; t < 2; ++t) {
        char* hb = (char*)&sP[wid][t][0][0];
        bf16x8 hA0 = *(const bf16x8*)(hb + lr * 128 + ((0  + lg * 16) ^ swz));
        bf16x8 hA1 = *(const bf16x8*)(hb + lr * 128 + ((64 + lg * 16) ^ swz));
        bf16x8 hB0 = *(const bf16x8*)(hb + 2048 + lr * 128 + ((0  + lg * 16) ^ swz));
        bf16x8 hB1 = *(const bf16x8*)(hb + 2048 + lr * 128 + ((64 + lg * 16) ^ swz));
        f32x4 u0[16] = {}, u1[16] = {};
        #pragma unroll
        for (int nt = 0; nt < 16; ++nt) {
            bf16x8 wA0 = *(const bf16x8*)(wsb + 32768 + ((size_t)((nt * 2 + 0) * 64 + l)) * 8);
            bf16x8 wA1 = *(const bf16x8*)(wsb + 32768 + ((size_t)((nt * 2 + 1) * 64 + l)) * 8);
            bf16x8 wB0 = *(const bf16x8*)(wsb + 49152 + ((size_t)((nt * 2 + 0) * 64 + l)) * 8);
            bf16x8 wB1 = *(const bf16x8*)(wsb + 49152 + ((size_t)((nt * 2 + 1) * 64 + l)) * 8);
            u0[nt] = __builtin_amdgcn_mfma_f32_16x16x32_bf16(wA0, hA0, u0[nt], 0, 0, 0);
            u0[nt] = __builtin_amdgcn_mfma_f32_16x16x32_bf16(wA1, hA1, u0[nt], 0, 0, 0);
            u1[nt] = __builtin_amdgcn_mfma_f32_16x16x32_bf16(wB0, hB0, u1[nt], 0, 0, 0);
            u1[nt] = __builtin_amdgcn_mfma_f32_16x16x32_bf16(wB1, hB1, u1[nt], 0, 0, 0);
        }
        float S0 = 0.f, Q20 = 0.f, S1 = 0.f, Q21 = 0.f;
        #pragma unroll
        for (int nt = 0; nt < 16; ++nt) {
            float4 bv0 = *(const float4*)(c1b2 + nt * 16 + lg * 4);
            float4 bv1 = *(const float4*)(c2b2 + nt * 16 + lg * 4);
            u0[nt][0] += bv0.x; u0[nt][1] += bv0.y; u0[nt][2] += bv0.z; u0[nt][3] += bv0.w;
            u1[nt][0] += bv1.x; u1[nt][1] += bv1.y; u1[nt][2] += bv1.z; u1[nt][3] += bv1.w;
            S0  += u0[nt][0] + u0[nt][1] + u0[nt][2] + u0[nt][3];
            Q20 += u0[nt][0] * u0[nt][0] + u0[nt][1] * u0[nt][1]
                 + u0[nt][2] * u0[nt][2] + u0[nt][3] * u0[nt][3];
            S1  += u1[nt][0] + u1[nt][1] + u1[nt][2] + u1[nt][3];
            Q21 += u1[nt][0] * u1[nt][0] + u1[nt][1] * u1[nt][1]
                 + u1[nt][2] * u1[nt][2] + u1[nt][3] * u1[nt][3];
        }
        S0  += __shfl_xor(S0, 16);  S0  += __shfl_xor(S0, 32);
        Q20 += __shfl_xor(Q20, 16); Q20 += __shfl_xor(Q20, 32);
        S1  += __shfl_xor(S1, 16);  S1  += __shfl_xor(S1, 32);
        Q21 += __shfl_xor(Q21, 16); Q21 += __shfl_xor(Q21, 32);
        float mu0 = S0 * (1.f / 256.f);
        float rs0 = rsqrtf(Q20 * (1.f / 256.f) - mu0 * mu0 + 1e-6f);
        float mu1 = S1 * (1.f / 256.f);
        float rs1 = rsqrtf(Q21 * (1.f / 256.f) - mu1 * mu1 + 1e-6f);
        char* pb = (char*)&sP[wid][t][0][0];
        #pragma unroll
        for (int nt = 0; nt < 16; ++nt) {
            float4 g0v = *(const float4*)(c1g  + nt * 16 + lg * 4);
            float4 e0v = *(const float4*)(c1be + nt * 16 + lg * 4);
            float4 g1v = *(const float4*)(c2g  + nt * 16 + lg * 4);
            float4 e1v = *(const float4*)(c2be + nt * 16 + lg * 4);
            float4 x0  = *(const float4*)(srow[t] + nt * 16 + lg * 4);
            float4 x1  = *(const float4*)(erow[t] + nt * 16 + lg * 4);
            float g04[4] = { g0v.x, g0v.y, g0v.z, g0v.w };
            float e04[4] = { e0v.x, e0v.y, e0v.z, e0v.w };
            float g14[4] = { g1v.x, g1v.y, g1v.z, g1v.w };
            float e14[4] = { e1v.x, e1v.y, e1v.z, e1v.w };
            float x04[4] = { x0.x, x0.y, x0.z, x0.w };
            float x14[4] = { x1.x, x1.y, x1.z, x1.w };
            float pm[4];
            #pragma unroll
            for (int r = 0; r < 4; ++r) {
                float ln0 = (u0[nt][r] - mu0) * rs0 * g04[r] + e04[r];
                float ln1 = (u1[nt][r] - mu1) * rs1 * g14[r] + e14[r];
                float sg0 = 1.f / (1.f + __expf(-ln0));
                float sg1 = 1.f / (1.f + __expf(-ln1));
                pm[r] = 0.5f * (sg0 * x04[r] + sg1 * x14[r]);
            }
            u32x2 wv;
            wv[0] = pk2(pm[0], pm[1]); wv[1] = pk2(pm[2], pm[3]);
            *(u32x2*)(pb + lr * 512 + ((nt * 32 + lg * 8) ^ swz)) = wv;
        }
    }
    asm volatile("s_waitcnt lgkmcnt(0)" ::: "memory");

    // ---------- gate B-frags: pooled (LDS) + qf (global), per tile ----------
    bf16x8 xf[2][16];
    #pragma unroll
    for (int t = 0; t < 2; ++t) {
        char* pb = (char*)&sP[wid][t][0][0];
        #pragma unroll
        for (int ks = 0; ks < 8; ++ks)
            xf[t][ks] = *(const bf16x8*)(pb + lr * 512 + ((ks * 64 + lg * 16) ^ swz));
        #pragma unroll
        for (int ks = 0; ks < 8; ++ks) {
            int k0 = ks * 32 + lg * 8;
            float4 q0v = *(const float4*)(qrow[t] + k0), q1v = *(const float4*)(qrow[t] + k0 + 4);
            u32x4 a;
            a[0] = pk2(q0v.x, q0v.y); a[1] = pk2(q0v.z, q0v.w);
            a[2] = pk2(q1v.x, q1v.y); a[3] = pk2(q1v.z, q1v.w);
            xf[t][8 + ks] = __builtin_bit_cast(bf16x8, a);
        }
    }
    asm volatile("s_waitcnt lgkmcnt(0)" ::: "memory");

    // ---------- gate GEMM + logits: weight frags shared across both tiles ----------
    float t0a[2] = {0.f, 0.f}, t1a[2] = {0.f, 0.f};
    const unsigned short* gwb = wsb + 65536;
    #pragma unroll
    for (int ntp = 0; ntp < 8; ++ntp) {
        f32x4 ga[2][2] = {};   // [tile][n-sub]
        #pragma unroll
        for (int kk = 0; kk < 16; ++kk) {
            bf16x8 wA = *(const bf16x8*)(gwb + ((size_t)(((ntp * 2 + 0) * 16 + kk) * 64 + l)) * 8);
            bf16x8 wB = *(const bf16x8*)(gwb + ((size_t)(((ntp * 2 + 1) * 16 + kk) * 64 + l)) * 8);
            ga[0][0] = __builtin_amdgcn_mfma_f32_16x16x32_bf16(wA, xf[0][kk], ga[0][0], 0, 0, 0);
            ga[1][0] = __builtin_amdgcn_mfma_f32_16x16x32_bf16(wA, xf[1][kk], ga[1][0], 0, 0, 0);
            ga[0][1] = __builtin_amdgcn_mfma_f32_16x16x32_bf16(wB, xf[0][kk], ga[0][1], 0, 0, 0);
            ga[1][1] = __builtin_amdgcn_mfma_f32_16x16x32_bf16(wB, xf[1][kk], ga[1][1], 0, 0, 0);
        }
        #pragma unroll
        for (int t2 = 0; t2 < 2; ++t2) {
            int nt = ntp * 2 + t2;
            float4 gbv = *(const float4*)(gb1 + nt * 16 + lg * 4);
            float4 w0v = *(const float4*)(gw2 + nt * 16 + lg * 4);
            float4 w1v = *(const float4*)(gw2 + 256 + nt * 16 + lg * 4);
            float gb4[4] = { gbv.x, gbv.y, gbv.z, gbv.w };
            float w04[4] = { w0v.x, w0v.y, w0v.z, w0v.w };
            float w14[4] = { w1v.x, w1v.y, w1v.z, w1v.w };
            #pragma unroll
            for (int t = 0; t < 2; ++t) {
                #pragma unroll
                for (int r = 0; r < 4; ++r) {
                    float hv = fmaxf(ga[t][t2][r] + gb4[r], 0.f);
                    t0a[t] += hv * w04[r]; t1a[t] += hv * w14[r];
                }
            }
        }
    }
    #pragma unroll
    for (int t = 0; t < 2; ++t) {
        t0a[t] += __shfl_xor(t0a[t], 16); t0a[t] += __shfl_xor(t0a[t], 32);
        t1a[t] += __shfl_xor(t1a[t], 16); t1a[t] += __shfl_xor(t1a[t], 32);
    }

    // ---------- epilogue: out = pooled*g0 + qf*(1-g0), straight from frags ----------
    #pragma unroll
    for (int t = 0; t < 2; ++t) {
        float g0 = 1.f / (1.f + __expf((t1a[t] + gb2[1]) - (t0a[t] + gb2[0])));
        float g1 = 1.f - g0;
        float* orow = out + (size_t)(rowb + t * 16 + lr) * C;
        #pragma unroll
        for (int ks = 0; ks < 8; ++ks) {
            u32x4 pu = __builtin_bit_cast(u32x4, xf[t][ks]);
            u32x4 qu = __builtin_bit_cast(u32x4, xf[t][8 + ks]);
            float4 o0, o1;
            o0.x = bflo(pu[0]) * g0 + bflo(qu[0]) * g1;
            o0.y = bfhi(pu[0]) * g0 + bfhi(qu[0]) * g1;
            o0.z = bflo(pu[1]) * g0 + bflo(qu[1]) * g1;
            o0.w = bfhi(pu[1]) * g0 + bfhi(qu[1]) * g1;
            o1.x = bflo(pu[2]) * g0 + bflo(qu[2]) * g1;
            o1.y = bfhi(pu[2]) * g0 + bfhi(qu[2]) * g1;
            o1.z = bflo(pu[3]) * g0 + bflo(qu[3]) * g1;
            o1.w = bfhi(pu[3]) * g0 + bfhi(qu[3]) * g1;
            *(float4*)(orow + ks * 32 + lg * 8)     = o0;
            *(float4*)(orow + ks * 32 + lg * 8 + 4) = o1;
        }
    }
}

extern "C" void kernel_launch(void* const* d_in, const int* in_sizes, int n_in,
                              void* d_out, int out_size, void* d_ws, size_t ws_size,
                              hipStream_t stream) {
    const float* feat  = (const float*)d_in[0];
    const float* qbox  = (const float*)d_in[1];
    const float* qfeat = (const float*)d_in[2];
    const float* posf  = (const float*)d_in[3];
    const float* c1w1  = (const float*)d_in[4];
    const float* c1b1  = (const float*)d_in[5];
    const float* c1w2  = (const float*)d_in[6];
    const float* c1b2  = (const float*)d_in[7];
    const float* c1g   = (const float*)d_in[8];
    const float* c1be  = (const float*)d_in[9];
    const float* c2w1  = (const float*)d_in[10];
    const float* c2b1  = (const float*)d_in[11];
    const float* c2w2  = (const float*)d_in[12];
    const float* c2b2  = (const float*)d_in[13];
    const float* c2g   = (const float*)d_in[14];
    const float* c2be  = (const float*)d_in[15];
    const float* gw1   = (const float*)d_in[16];
    const float* gb1   = (const float*)d_in[17];
    const float* gw2   = (const float*)d_in[18];
    const float* gb2   = (const float*)d_in[19];
    float* out = (float*)d_out;
    unsigned short* wsb = (unsigned short*)d_ws;   // 393216 B used

    prep_weights<<<96, 256, 0, stream>>>(c1w1, c2w1, c1w2, c2w2, gw1, wsb);

    dim3 grid((NB * NQ) / 128), block(256);        // 512 blocks, 4 waves, 32 rows/wave
    semalign_v5<<<grid, block, 0, stream>>>(
        feat, qbox, qfeat, posf,
        c1b1, c1b2, c1g, c1be,
        c2b1, c2b2, c2g, c2be,
        gb1, gw2, gb2, wsb, out);
}

// Round 6
// 294.833 us; speedup vs baseline: 1.0172x; 1.0172x over previous
//
#include <hip/hip_runtime.h>
#include <hip/hip_bf16.h>
#include <math.h>

typedef __attribute__((ext_vector_type(8))) short bf16x8;
typedef __attribute__((ext_vector_type(4))) float f32x4;
typedef __attribute__((ext_vector_type(4))) unsigned int u32x4;
typedef __attribute__((ext_vector_type(2))) unsigned int u32x2;

constexpr int NB = 16, NQ = 4096, LF = 2048, C = 256;

__device__ __forceinline__ unsigned short bfbits(float x) {
    return __builtin_bit_cast(unsigned short, __float2bfloat16(x));
}
__device__ __forceinline__ unsigned pk2(float a, float b) {
    return (unsigned)bfbits(a) | ((unsigned)bfbits(b) << 16);
}
__device__ __forceinline__ float bflo(unsigned d) { return __builtin_bit_cast(float, d << 16); }
__device__ __forceinline__ float bfhi(unsigned d) { return __builtin_bit_cast(float, d & 0xffff0000u); }

// ---- prep: weights -> bf16 fragment-linear layout in ws (unchanged, verified) ----
// frag s stride 1024 B, lane l at +l*16. chunk c (32 KiB) base = c*32768 B.
// chunks: 0=w1c1, 1=w1c2, 2=w2c1, 3=w2c2, 4..11=gw1
__global__ void prep_weights(const float* __restrict__ c1w1, const float* __restrict__ c2w1,
                             const float* __restrict__ c1w2, const float* __restrict__ c2w2,
                             const float* __restrict__ gw1, unsigned short* __restrict__ ws)
{
    int t = blockIdx.x * 256 + threadIdx.x;          // 0..24575
    const float* src; int K, nks, dstoff, f;
    if (t < 2048)      { src = c1w1; K = 256; nks = 8;  dstoff = 0;      f = t; }
    else if (t < 4096) { src = c2w1; K = 256; nks = 8;  dstoff = 16384;  f = t - 2048; }
    else if (t < 6144) { src = c1w2; K = 64;  nks = 2;  dstoff = 32768;  f = t - 4096; }
    else if (t < 8192) { src = c2w2; K = 64;  nks = 2;  dstoff = 49152;  f = t - 6144; }
    else               { src = gw1;  K = 512; nks = 16; dstoff = 65536;  f = t - 8192; }
    int l = f & 63, s = f >> 6;
    int nt = s / nks, ks = s % nks;
    int n  = nt * 16 + (l & 15);
    int k0 = ks * 32 + (l >> 4) * 8;
    unsigned short* d = ws + dstoff + (size_t)f * 8;
    const float* sp = src + (size_t)n * K + k0;
    #pragma unroll
    for (int e = 0; e < 8; ++e) d[e] = bfbits(sp[e]);
}

// async stage one 32 KiB chunk (32 frags): wave wid stages frags wid*4..wid*4+3
__device__ __forceinline__ void stage_chunk(const unsigned short* wsb, int chunk,
                                            unsigned short* dst, int wid, int l)
{
    const char* g = (const char*)wsb + (size_t)chunk * 32768 + (size_t)wid * 4096 + (size_t)l * 16;
    char* d = (char*)dst + wid * 4096;
    #pragma unroll
    for (int i = 0; i < 4; ++i) {
        __builtin_amdgcn_global_load_lds(
            (const __attribute__((address_space(1))) void*)(g + i * 1024),
            (__attribute__((address_space(3))) void*)(d + i * 1024),
            16, 0, 0);
    }
}

// ---- main: 8 waves/block, LDS-staged weights (double-buffered), v4 math per wave ----
__global__ __launch_bounds__(512, 2)
void semalign_v6(const float* __restrict__ feat,  const float* __restrict__ qbox,
                 const float* __restrict__ qfeat, const float* __restrict__ posf,
                 const float* __restrict__ c1b1,  const float* __restrict__ c1b2,
                 const float* __restrict__ c1g,   const float* __restrict__ c1be,
                 const float* __restrict__ c2b1,  const float* __restrict__ c2b2,
                 const float* __restrict__ c2g,   const float* __restrict__ c2be,
                 const float* __restrict__ gb1,   const float* __restrict__ gw2,
                 const float* __restrict__ gb2,
                 const unsigned short* __restrict__ wsb,
                 float* __restrict__ out)
{
    __shared__ __align__(16) unsigned short sW[2][16384];    // 2 x 32 KiB weight staging
    __shared__ __align__(16) unsigned short sP[8][16][256];  // 8 x 8 KiB per-wave H/pooled

    const int tid = threadIdx.x, l = tid & 63, wid = tid >> 6;   // 8 waves
    const int lr = l & 15, lg = l >> 4;
    const int rowb = blockIdx.x * 128 + wid * 16;
    const int q = rowb >> 4;
    const int b = lr;
    const int swz = (lr & 7) << 4;

    // kick off staging of the first two chunks before anything else
    stage_chunk(wsb, 0, sW[0], wid, l);
    stage_chunk(wsb, 1, sW[1], wid, l);

    const float* prow = posf  + ((size_t)b * NQ + q) * C;
    const float* qrow = qfeat + ((size_t)b * NQ + q) * C;
    float cx = qbox[((size_t)b * NQ + q) * 2 + 0];
    float w  = qbox[((size_t)b * NQ + q) * 2 + 1];
    float fs = fminf(fmaxf((cx - 0.5f * w) * (float)LF, 0.f), (float)(LF - 1));
    float fe = fminf(fmaxf((cx + 0.5f * w) * (float)LF, 0.f), (float)(LF - 1));
    const float* srow = feat + ((size_t)b * LF + (int)rintf(fs)) * C;
    const float* erow = feat + ((size_t)b * LF + (int)rintf(fe)) * C;

    // activation B-frags from global (overlaps with staging)
    bf16x8 v1f[8], v2f[8];
    #pragma unroll
    for (int ks = 0; ks < 8; ++ks) {
        int k0 = ks * 32 + lg * 8;
        float4 s0 = *(const float4*)(srow + k0), s1 = *(const float4*)(srow + k0 + 4);
        float4 e0 = *(const float4*)(erow + k0), e1 = *(const float4*)(erow + k0 + 4);
        float4 p0 = *(const float4*)(prow + k0), p1 = *(const float4*)(prow + k0 + 4);
        u32x4 a, c;
        a[0] = pk2(s0.x * p0.x, s0.y * p0.y); a[1] = pk2(s0.z * p0.z, s0.w * p0.w);
        a[2] = pk2(s1.x * p1.x, s1.y * p1.y); a[3] = pk2(s1.z * p1.z, s1.w * p1.w);
        c[0] = pk2(e0.x * p0.x, e0.y * p0.y); c[1] = pk2(e0.z * p0.z, e0.w * p0.w);
        c[2] = pk2(e1.x * p1.x, e1.y * p1.y); c[3] = pk2(e1.z * p1.z, e1.w * p1.w);
        v1f[ks] = __builtin_bit_cast(bf16x8, a);
        v2f[ks] = __builtin_bit_cast(bf16x8, c);
    }

    __syncthreads();                       // chunks 0,1 staged

    // ---------- chunk0: GEMM1 contrast1 ----------
    f32x4 a1[4] = {};
    {
        const char* wb = (const char*)sW[0];
        #pragma unroll
        for (int ks = 0; ks < 8; ++ks)
            #pragma unroll
            for (int nt = 0; nt < 4; ++nt) {
                bf16x8 wA = *(const bf16x8*)(wb + (nt * 8 + ks) * 1024 + l * 16);
                a1[nt] = __builtin_amdgcn_mfma_f32_16x16x32_bf16(wA, v1f[ks], a1[nt], 0, 0, 0);
            }
    }
    __syncthreads();
    stage_chunk(wsb, 2, sW[0], wid, l);

    // ---------- chunk1: GEMM1 contrast2 + H pack + H frag reads ----------
    char* hb = (char*)&sP[wid][0][0];
    bf16x8 hA0, hA1, hB0, hB1;
    {
        const char* wb = (const char*)sW[1];
        f32x4 a2[4] = {};
        #pragma unroll
        for (int ks = 0; ks < 8; ++ks)
            #pragma unroll
            for (int nt = 0; nt < 4; ++nt) {
                bf16x8 wB = *(const bf16x8*)(wb + (nt * 8 + ks) * 1024 + l * 16);
                a2[nt] = __builtin_amdgcn_mfma_f32_16x16x32_bf16(wB, v2f[ks], a2[nt], 0, 0, 0);
            }
        #pragma unroll
        for (int nt = 0; nt < 4; ++nt) {
            float4 b1v = *(const float4*)(c1b1 + nt * 16 + lg * 4);
            float4 b2v = *(const float4*)(c2b1 + nt * 16 + lg * 4);
            u32x2 wv;
            wv[0] = pk2(fmaxf(a1[nt][0] + b1v.x, 0.f), fmaxf(a1[nt][1] + b1v.y, 0.f));
            wv[1] = pk2(fmaxf(a1[nt][2] + b1v.z, 0.f), fmaxf(a1[nt][3] + b1v.w, 0.f));
            *(u32x2*)(hb + lr * 128 + ((nt * 32 + lg * 8) ^ swz)) = wv;
            wv[0] = pk2(fmaxf(a2[nt][0] + b2v.x, 0.f), fmaxf(a2[nt][1] + b2v.y, 0.f));
            wv[1] = pk2(fmaxf(a2[nt][2] + b2v.z, 0.f), fmaxf(a2[nt][3] + b2v.w, 0.f));
            *(u32x2*)(hb + 2048 + lr * 128 + ((nt * 32 + lg * 8) ^ swz)) = wv;
        }
        asm volatile("s_waitcnt lgkmcnt(0)" ::: "memory");
        hA0 = *(const bf16x8*)(hb + lr * 128 + ((0  + lg * 16) ^ swz));
        hA1 = *(const bf16x8*)(hb + lr * 128 + ((64 + lg * 16) ^ swz));
        hB0 = *(const bf16x8*)(hb + 2048 + lr * 128 + ((0  + lg * 16) ^ swz));
        hB1 = *(const bf16x8*)(hb + 2048 + lr * 128 + ((64 + lg * 16) ^ swz));
    }
    __syncthreads();
    stage_chunk(wsb, 3, sW[1], wid, l);

    // ---------- chunk2: GEMM2 contrast1 + LN1 + sigmoid -> pooled partial ----------
    f32x4 p[16];
    {
        const char* wb = (const char*)sW[0];
        f32x4 u0[16] = {};
        #pragma unroll
        for (int nt = 0; nt < 16; ++nt) {
            bf16x8 wA0 = *(const bf16x8*)(wb + (nt * 2 + 0) * 1024 + l * 16);
            bf16x8 wA1 = *(const bf16x8*)(wb + (nt * 2 + 1) * 1024 + l * 16);
            u0[nt] = __builtin_amdgcn_mfma_f32_16x16x32_bf16(wA0, hA0, u0[nt], 0, 0, 0);
            u0[nt] = __builtin_amdgcn_mfma_f32_16x16x32_bf16(wA1, hA1, u0[nt], 0, 0, 0);
        }
        float S = 0.f, Q2 = 0.f;
        #pragma unroll
        for (int nt = 0; nt < 16; ++nt) {
            float4 bv = *(const float4*)(c1b2 + nt * 16 + lg * 4);
            u0[nt][0] += bv.x; u0[nt][1] += bv.y; u0[nt][2] += bv.z; u0[nt][3] += bv.w;
            S  += u0[nt][0] + u0[nt][1] + u0[nt][2] + u0[nt][3];
            Q2 += u0[nt][0] * u0[nt][0] + u0[nt][1] * u0[nt][1]
                + u0[nt][2] * u0[nt][2] + u0[nt][3] * u0[nt][3];
        }
        S  += __shfl_xor(S, 16);  S  += __shfl_xor(S, 32);
        Q2 += __shfl_xor(Q2, 16); Q2 += __shfl_xor(Q2, 32);
        float mu  = S * (1.f / 256.f);
        float rsg = rsqrtf(Q2 * (1.f / 256.f) - mu * mu + 1e-6f);
        #pragma unroll
        for (int nt = 0; nt < 16; ++nt) {
            float4 gv  = *(const float4*)(c1g  + nt * 16 + lg * 4);
            float4 bev = *(const float4*)(c1be + nt * 16 + lg * 4);
            float4 xv  = *(const float4*)(srow + nt * 16 + lg * 4);
            float g4[4] = { gv.x, gv.y, gv.z, gv.w };
            float e4[4] = { bev.x, bev.y, bev.z, bev.w };
            float x4[4] = { xv.x, xv.y, xv.z, xv.w };
            #pragma unroll
            for (int r = 0; r < 4; ++r) {
                float ln = (u0[nt][r] - mu) * rsg * g4[r] + e4[r];
                float sg = 1.f / (1.f + __expf(-ln));
                p[nt][r] = 0.5f * sg * x4[r];
            }
        }
    }
    __syncthreads();
    stage_chunk(wsb, 4, sW[0], wid, l);

    // ---------- chunk3: GEMM2 contrast2 + LN2 -> pooled to LDS, build gate frags ----------
    bf16x8 xf[16];
    {
        const char* wb = (const char*)sW[1];
        f32x4 u1[16] = {};
        #pragma unroll
        for (int nt = 0; nt < 16; ++nt) {
            bf16x8 wB0 = *(const bf16x8*)(wb + (nt * 2 + 0) * 1024 + l * 16);
            bf16x8 wB1 = *(const bf16x8*)(wb + (nt * 2 + 1) * 1024 + l * 16);
            u1[nt] = __builtin_amdgcn_mfma_f32_16x16x32_bf16(wB0, hB0, u1[nt], 0, 0, 0);
            u1[nt] = __builtin_amdgcn_mfma_f32_16x16x32_bf16(wB1, hB1, u1[nt], 0, 0, 0);
        }
        float S = 0.f, Q2 = 0.f;
        #pragma unroll
        for (int nt = 0; nt < 16; ++nt) {
            float4 bv = *(const float4*)(c2b2 + nt * 16 + lg * 4);
            u1[nt][0] += bv.x; u1[nt][1] += bv.y; u1[nt][2] += bv.z; u1[nt][3] += bv.w;
            S  += u1[nt][0] + u1[nt][1] + u1[nt][2] + u1[nt][3];
            Q2 += u1[nt][0] * u1[nt][0] + u1[nt][1] * u1[nt][1]
                + u1[nt][2] * u1[nt][2] + u1[nt][3] * u1[nt][3];
        }
        S  += __shfl_xor(S, 16);  S  += __shfl_xor(S, 32);
        Q2 += __shfl_xor(Q2, 16); Q2 += __shfl_xor(Q2, 32);
        float mu  = S * (1.f / 256.f);
        float rsg = rsqrtf(Q2 * (1.f / 256.f) - mu * mu + 1e-6f);
        #pragma unroll
        for (int nt = 0; nt < 16; ++nt) {
            float4 gv  = *(const float4*)(c2g  + nt * 16 + lg * 4);
            float4 bev = *(const float4*)(c2be + nt * 16 + lg * 4);
            float4 xv  = *(const float4*)(erow + nt * 16 + lg * 4);
            float g4[4] = { gv.x, gv.y, gv.z, gv.w };
            float e4[4] = { bev.x, bev.y, bev.z, bev.w };
            float x4[4] = { xv.x, xv.y, xv.z, xv.w };
            float pm[4];
            #pragma unroll
            for (int r = 0; r < 4; ++r) {
                float ln = (u1[nt][r] - mu) * rsg * g4[r] + e4[r];
                float sg = 1.f / (1.f + __expf(-ln));
                pm[r] = p[nt][r] + 0.5f * sg * x4[r];
            }
            u32x2 wv;
            wv[0] = pk2(pm[0], pm[1]); wv[1] = pk2(pm[2], pm[3]);
            *(u32x2*)(hb + lr * 512 + ((nt * 32 + lg * 8) ^ swz)) = wv;
        }
        asm volatile("s_waitcnt lgkmcnt(0)" ::: "memory");
        #pragma unroll
        for (int ks = 0; ks < 8; ++ks)
            xf[ks] = *(const bf16x8*)(hb + lr * 512 + ((ks * 64 + lg * 16) ^ swz));
        #pragma unroll
        for (int ks = 0; ks < 8; ++ks) {
            int k0 = ks * 32 + lg * 8;
            float4 q0v = *(const float4*)(qrow + k0), q1v = *(const float4*)(qrow + k0 + 4);
            u32x4 a;
            a[0] = pk2(q0v.x, q0v.y); a[1] = pk2(q0v.z, q0v.w);
            a[2] = pk2(q1v.x, q1v.y); a[3] = pk2(q1v.z, q1v.w);
            xf[8 + ks] = __builtin_bit_cast(bf16x8, a);
        }
    }
    __syncthreads();
    stage_chunk(wsb, 5, sW[1], wid, l);

    // ---------- chunks 4..11: gate GEMM (gw1) + logit folding ----------
    float t0 = 0.f, t1 = 0.f;
    #pragma unroll
    for (int c = 4; c <= 11; ++c) {
        const char* wb = (const char*)sW[c & 1];
        f32x4 ga0 = {}, ga1 = {};
        #pragma unroll
        for (int kk = 0; kk < 16; ++kk) {
            bf16x8 wA = *(const bf16x8*)(wb + kk * 1024 + l * 16);
            bf16x8 wB = *(const bf16x8*)(wb + (16 + kk) * 1024 + l * 16);
            ga0 = __builtin_amdgcn_mfma_f32_16x16x32_bf16(wA, xf[kk], ga0, 0, 0, 0);
            ga1 = __builtin_amdgcn_mfma_f32_16x16x32_bf16(wB, xf[kk], ga1, 0, 0, 0);
        }
        int n0 = (c - 4) * 2;
        #pragma unroll
        for (int t2 = 0; t2 < 2; ++t2) {
            f32x4 ga = t2 ? ga1 : ga0;
            int nt = n0 + t2;
            float4 gbv = *(const float4*)(gb1 + nt * 16 + lg * 4);
            float4 w0v = *(const float4*)(gw2 + nt * 16 + lg * 4);
            float4 w1v = *(const float4*)(gw2 + 256 + nt * 16 + lg * 4);
            float gb4[4] = { gbv.x, gbv.y, gbv.z, gbv.w };
            float w04[4] = { w0v.x, w0v.y, w0v.z, w0v.w };
            float w14[4] = { w1v.x, w1v.y, w1v.z, w1v.w };
            #pragma unroll
            for (int r = 0; r < 4; ++r) {
                float hv = fmaxf(ga[r] + gb4[r], 0.f);
                t0 += hv * w04[r]; t1 += hv * w14[r];
            }
        }
        __syncthreads();
        if (c + 2 <= 11) stage_chunk(wsb, c + 2, sW[c & 1], wid, l);
    }

    // ---------- logits + softmax(2) + store ----------
    t0 += __shfl_xor(t0, 16); t0 += __shfl_xor(t0, 32);
    t1 += __shfl_xor(t1, 16); t1 += __shfl_xor(t1, 32);
    float g0 = 1.f / (1.f + __expf((t1 + gb2[1]) - (t0 + gb2[0])));
    float g1v = 1.f - g0;

    float* orow = out + (size_t)(rowb + lr) * C;
    #pragma unroll
    for (int ks = 0; ks < 8; ++ks) {
        u32x4 pu = __builtin_bit_cast(u32x4, xf[ks]);
        u32x4 qu = __builtin_bit_cast(u32x4, xf[8 + ks]);
        float4 o0, o1;
        o0.x = bflo(pu[0]) * g0 + bflo(qu[0]) * g1v;
        o0.y = bfhi(pu[0]) * g0 + bfhi(qu[0]) * g1v;
        o0.z = bflo(pu[1]) * g0 + bflo(qu[1]) * g1v;
        o0.w = bfhi(pu[1]) * g0 + bfhi(qu[1]) * g1v;
        o1.x = bflo(pu[2]) * g0 + bflo(qu[2]) * g1v;
        o1.y = bfhi(pu[2]) * g0 + bfhi(qu[2]) * g1v;
        o1.z = bflo(pu[3]) * g0 + bflo(qu[3]) * g1v;
        o1.w = bfhi(pu[3]) * g0 + bfhi(qu[3]) * g1v;
        *(float4*)(orow + ks * 32 + lg * 8)     = o0;
        *(float4*)(orow + ks * 32 + lg * 8 + 4) = o1;
    }
}

extern "C" void kernel_launch(void* const* d_in, const int* in_sizes, int n_in,
                              void* d_out, int out_size, void* d_ws, size_t ws_size,
                              hipStream_t stream) {
    const float* feat  = (const float*)d_in[0];
    const float* qbox  = (const float*)d_in[1];
    const float* qfeat = (const float*)d_in[2];
    const float* posf  = (const float*)d_in[3];
    const float* c1w1  = (const float*)d_in[4];
    const float* c1b1  = (const float*)d_in[5];
    const float* c1w2  = (const float*)d_in[6];
    const float* c1b2  = (const float*)d_in[7];
    const float* c1g   = (const float*)d_in[8];
    const float* c1be  = (const float*)d_in[9];
    const float* c2w1  = (const float*)d_in[10];
    const float* c2b1  = (const float*)d_in[11];
    const float* c2w2  = (const float*)d_in[12];
    const float* c2b2  = (const float*)d_in[13];
    const float* c2g   = (const float*)d_in[14];
    const float* c2be  = (const float*)d_in[15];
    const float* gw1   = (const float*)d_in[16];
    const float* gb1   = (const float*)d_in[17];
    const float* gw2   = (const float*)d_in[18];
    const float* gb2   = (const float*)d_in[19];
    float* out = (float*)d_out;
    unsigned short* wsb = (unsigned short*)d_ws;   // 393216 B used

    prep_weights<<<96, 256, 0, stream>>>(c1w1, c2w1, c1w2, c2w2, gw1, wsb);

    dim3 grid((NB * NQ) / 128), block(512);        // 512 blocks, 8 waves, 16 rows/wave
    semalign_v6<<<grid, block, 0, stream>>>(
        feat, qbox, qfeat, posf,
        c1b1, c1b2, c1g, c1be,
        c2b1, c2b2, c2g, c2be,
        gb1, gw2, gb2, wsb, out);
}

// Round 7
// 182.929 us; speedup vs baseline: 1.6394x; 1.6117x over previous
//
#include <hip/hip_runtime.h>
#include <hip/hip_bf16.h>
#include <math.h>

typedef __attribute__((ext_vector_type(8))) short bf16x8;
typedef __attribute__((ext_vector_type(4))) float f32x4;
typedef __attribute__((ext_vector_type(2))) __fp16 f16x2;
typedef __attribute__((ext_vector_type(4))) unsigned int u32x4;
typedef __attribute__((ext_vector_type(2))) unsigned int u32x2;

constexpr int NB = 16, NQ = 4096, LF = 2048, C = 256;

__device__ __forceinline__ unsigned short bfbits(float x) {
    return __builtin_bit_cast(unsigned short, __float2bfloat16(x));
}
__device__ __forceinline__ unsigned pk2(float a, float b) {
    return (unsigned)bfbits(a) | ((unsigned)bfbits(b) << 16);
}
__device__ __forceinline__ float bflo(unsigned d) { return __builtin_bit_cast(float, d << 16); }
__device__ __forceinline__ float bfhi(unsigned d) { return __builtin_bit_cast(float, d & 0xffff0000u); }

// ---- prep: weights -> bf16 fragment-linear layout in ws (verified) ----
// chunk c (32 KiB = 32 frags) base = c*16384 ushorts.
// chunks: 0=w1c1, 1=w1c2, 2=w2c1, 3=w2c2, 4..11=gw1
__global__ void prep_weights(const float* __restrict__ c1w1, const float* __restrict__ c2w1,
                             const float* __restrict__ c1w2, const float* __restrict__ c2w2,
                             const float* __restrict__ gw1, unsigned short* __restrict__ ws)
{
    int t = blockIdx.x * 256 + threadIdx.x;          // 0..24575
    const float* src; int K, nks, dstoff, f;
    if (t < 2048)      { src = c1w1; K = 256; nks = 8;  dstoff = 0;      f = t; }
    else if (t < 4096) { src = c2w1; K = 256; nks = 8;  dstoff = 16384;  f = t - 2048; }
    else if (t < 6144) { src = c1w2; K = 64;  nks = 2;  dstoff = 32768;  f = t - 4096; }
    else if (t < 8192) { src = c2w2; K = 64;  nks = 2;  dstoff = 49152;  f = t - 6144; }
    else               { src = gw1;  K = 512; nks = 16; dstoff = 65536;  f = t - 8192; }
    int l = f & 63, s = f >> 6;
    int nt = s / nks, ks = s % nks;
    int n  = nt * 16 + (l & 15);
    int k0 = ks * 32 + (l >> 4) * 8;
    unsigned short* d = ws + dstoff + (size_t)f * 8;
    const float* sp = src + (size_t)n * K + k0;
    #pragma unroll
    for (int e = 0; e < 8; ++e) d[e] = bfbits(sp[e]);
}

// stage one 32 KiB chunk with 128 threads: 16 x global_load_lds(16B) per lane
__device__ __forceinline__ void stage_chunk(const unsigned short* wsb, int chunk,
                                            unsigned short* dst, int wid, int l)
{
    const char* g = (const char*)wsb + (size_t)chunk * 32768 + wid * 1024 + (size_t)l * 16;
    char* d = (char*)dst + wid * 1024;
    #pragma unroll
    for (int i = 0; i < 16; ++i) {
        __builtin_amdgcn_global_load_lds(
            (const __attribute__((address_space(1))) void*)(g + i * 2048),
            (__attribute__((address_space(3))) void*)(d + i * 2048),
            16, 0, 0);
    }
}

// ---- main: 2 waves/block, double-buffered LDS weight streaming, v4 math ----
__global__ __launch_bounds__(128, 2)
void semalign_v7(const float* __restrict__ feat,  const float* __restrict__ qbox,
                 const float* __restrict__ qfeat, const float* __restrict__ posf,
                 const float* __restrict__ c1b1,  const float* __restrict__ c1b2,
                 const float* __restrict__ c1g,   const float* __restrict__ c1be,
                 const float* __restrict__ c2b1,  const float* __restrict__ c2b2,
                 const float* __restrict__ c2g,   const float* __restrict__ c2be,
                 const float* __restrict__ gb1,   const float* __restrict__ gw2,
                 const float* __restrict__ gb2,
                 const unsigned short* __restrict__ wsb,
                 float* __restrict__ out)
{
    __shared__ __align__(16) unsigned short sW[2][16384];    // 2 x 32 KiB weight buffers
    __shared__ __align__(16) unsigned short sP[2][16][256];  // 2 x 8 KiB per-wave H/pooled

    const int tid = threadIdx.x, l = tid & 63, wid = tid >> 6;   // 2 waves
    const int lr = l & 15, lg = l >> 4;
    const int rowb = blockIdx.x * 32 + wid * 16;
    const int q = rowb >> 4;
    const int b = lr;
    const int swz = (lr & 7) << 4;

    stage_chunk(wsb, 0, sW[0], wid, l);
    stage_chunk(wsb, 1, sW[1], wid, l);

    const float* prow = posf  + ((size_t)b * NQ + q) * C;
    const float* qrow = qfeat + ((size_t)b * NQ + q) * C;
    float cx = qbox[((size_t)b * NQ + q) * 2 + 0];
    float w  = qbox[((size_t)b * NQ + q) * 2 + 1];
    float fs = fminf(fmaxf((cx - 0.5f * w) * (float)LF, 0.f), (float)(LF - 1));
    float fe = fminf(fmaxf((cx + 0.5f * w) * (float)LF, 0.f), (float)(LF - 1));
    const float* srow = feat + ((size_t)b * LF + (int)rintf(fs)) * C;
    const float* erow = feat + ((size_t)b * LF + (int)rintf(fe)) * C;

    // activation B-frags from global (overlaps with staging)
    bf16x8 v1f[8], v2f[8];
    #pragma unroll
    for (int ks = 0; ks < 8; ++ks) {
        int k0 = ks * 32 + lg * 8;
        float4 s0 = *(const float4*)(srow + k0), s1 = *(const float4*)(srow + k0 + 4);
        float4 e0 = *(const float4*)(erow + k0), e1 = *(const float4*)(erow + k0 + 4);
        float4 p0 = *(const float4*)(prow + k0), p1 = *(const float4*)(prow + k0 + 4);
        u32x4 a, c;
        a[0] = pk2(s0.x * p0.x, s0.y * p0.y); a[1] = pk2(s0.z * p0.z, s0.w * p0.w);
        a[2] = pk2(s1.x * p1.x, s1.y * p1.y); a[3] = pk2(s1.z * p1.z, s1.w * p1.w);
        c[0] = pk2(e0.x * p0.x, e0.y * p0.y); c[1] = pk2(e0.z * p0.z, e0.w * p0.w);
        c[2] = pk2(e1.x * p1.x, e1.y * p1.y); c[3] = pk2(e1.z * p1.z, e1.w * p1.w);
        v1f[ks] = __builtin_bit_cast(bf16x8, a);
        v2f[ks] = __builtin_bit_cast(bf16x8, c);
    }

    __syncthreads();                                  // chunks 0,1 resident

    // ---------- chunk0: GEMM1 contrast1 ----------
    f32x4 a1[4] = {};
    {
        const char* wb = (const char*)sW[0];
        #pragma unroll
        for (int ks = 0; ks < 8; ++ks)
            #pragma unroll
            for (int nt = 0; nt < 4; ++nt) {
                bf16x8 wA = *(const bf16x8*)(wb + (nt * 8 + ks) * 1024 + l * 16);
                a1[nt] = __builtin_amdgcn_mfma_f32_16x16x32_bf16(wA, v1f[ks], a1[nt], 0, 0, 0);
            }
    }
    __syncthreads();
    stage_chunk(wsb, 2, sW[0], wid, l);

    // ---------- chunk1: GEMM1 contrast2 + H pack + H frag reads ----------
    char* hb = (char*)&sP[wid][0][0];
    bf16x8 hA0, hA1, hB0, hB1;
    {
        const char* wb = (const char*)sW[1];
        f32x4 a2[4] = {};
        #pragma unroll
        for (int ks = 0; ks < 8; ++ks)
            #pragma unroll
            for (int nt = 0; nt < 4; ++nt) {
                bf16x8 wB = *(const bf16x8*)(wb + (nt * 8 + ks) * 1024 + l * 16);
                a2[nt] = __builtin_amdgcn_mfma_f32_16x16x32_bf16(wB, v2f[ks], a2[nt], 0, 0, 0);
            }
        #pragma unroll
        for (int nt = 0; nt < 4; ++nt) {
            float4 b1v = *(const float4*)(c1b1 + nt * 16 + lg * 4);
            float4 b2v = *(const float4*)(c2b1 + nt * 16 + lg * 4);
            u32x2 wv;
            wv[0] = pk2(fmaxf(a1[nt][0] + b1v.x, 0.f), fmaxf(a1[nt][1] + b1v.y, 0.f));
            wv[1] = pk2(fmaxf(a1[nt][2] + b1v.z, 0.f), fmaxf(a1[nt][3] + b1v.w, 0.f));
            *(u32x2*)(hb + lr * 128 + ((nt * 32 + lg * 8) ^ swz)) = wv;
            wv[0] = pk2(fmaxf(a2[nt][0] + b2v.x, 0.f), fmaxf(a2[nt][1] + b2v.y, 0.f));
            wv[1] = pk2(fmaxf(a2[nt][2] + b2v.z, 0.f), fmaxf(a2[nt][3] + b2v.w, 0.f));
            *(u32x2*)(hb + 2048 + lr * 128 + ((nt * 32 + lg * 8) ^ swz)) = wv;
        }
        asm volatile("s_waitcnt lgkmcnt(0)" ::: "memory");
        hA0 = *(const bf16x8*)(hb + lr * 128 + ((0  + lg * 16) ^ swz));
        hA1 = *(const bf16x8*)(hb + lr * 128 + ((64 + lg * 16) ^ swz));
        hB0 = *(const bf16x8*)(hb + 2048 + lr * 128 + ((0  + lg * 16) ^ swz));
        hB1 = *(const bf16x8*)(hb + 2048 + lr * 128 + ((64 + lg * 16) ^ swz));
    }
    __syncthreads();
    stage_chunk(wsb, 3, sW[1], wid, l);

    // ---------- chunk2: GEMM2 contrast1 + LN1 -> Ph (packed fp16, 32 regs) ----------
    f16x2 Ph[16][2];
    {
        const char* wb = (const char*)sW[0];
        f32x4 u0[16] = {};
        #pragma unroll
        for (int nt = 0; nt < 16; ++nt) {
            bf16x8 wA0 = *(const bf16x8*)(wb + (nt * 2 + 0) * 1024 + l * 16);
            bf16x8 wA1 = *(const bf16x8*)(wb + (nt * 2 + 1) * 1024 + l * 16);
            u0[nt] = __builtin_amdgcn_mfma_f32_16x16x32_bf16(wA0, hA0, u0[nt], 0, 0, 0);
            u0[nt] = __builtin_amdgcn_mfma_f32_16x16x32_bf16(wA1, hA1, u0[nt], 0, 0, 0);
        }
        float S = 0.f, Q2 = 0.f;
        #pragma unroll
        for (int nt = 0; nt < 16; ++nt) {
            float4 bv = *(const float4*)(c1b2 + nt * 16 + lg * 4);
            u0[nt][0] += bv.x; u0[nt][1] += bv.y; u0[nt][2] += bv.z; u0[nt][3] += bv.w;
            S  += u0[nt][0] + u0[nt][1] + u0[nt][2] + u0[nt][3];
            Q2 += u0[nt][0] * u0[nt][0] + u0[nt][1] * u0[nt][1]
                + u0[nt][2] * u0[nt][2] + u0[nt][3] * u0[nt][3];
        }
        S  += __shfl_xor(S, 16);  S  += __shfl_xor(S, 32);
        Q2 += __shfl_xor(Q2, 16); Q2 += __shfl_xor(Q2, 32);
        float mu  = S * (1.f / 256.f);
        float rsg = rsqrtf(Q2 * (1.f / 256.f) - mu * mu + 1e-6f);
        #pragma unroll
        for (int nt = 0; nt < 16; ++nt) {
            float4 gv  = *(const float4*)(c1g  + nt * 16 + lg * 4);
            float4 bev = *(const float4*)(c1be + nt * 16 + lg * 4);
            float4 xv  = *(const float4*)(srow + nt * 16 + lg * 4);
            float g4[4] = { gv.x, gv.y, gv.z, gv.w };
            float e4[4] = { bev.x, bev.y, bev.z, bev.w };
            float x4[4] = { xv.x, xv.y, xv.z, xv.w };
            float tm[4];
            #pragma unroll
            for (int r = 0; r < 4; ++r) {
                float ln = (u0[nt][r] - mu) * rsg * g4[r] + e4[r];
                float sg = 1.f / (1.f + __expf(-ln));
                tm[r] = 0.5f * sg * x4[r];
            }
            Ph[nt][0] = __builtin_amdgcn_cvt_pkrtz(tm[0], tm[1]);
            Ph[nt][1] = __builtin_amdgcn_cvt_pkrtz(tm[2], tm[3]);
        }
    }
    __syncthreads();
    stage_chunk(wsb, 4, sW[0], wid, l);

    // ---------- chunk3: GEMM2 contrast2 + LN2 -> pooled to sP; qf frags ----------
    bf16x8 qff[8];
    {
        const char* wb = (const char*)sW[1];
        f32x4 u1[16] = {};
        #pragma unroll
        for (int nt = 0; nt < 16; ++nt) {
            bf16x8 wB0 = *(const bf16x8*)(wb + (nt * 2 + 0) * 1024 + l * 16);
            bf16x8 wB1 = *(const bf16x8*)(wb + (nt * 2 + 1) * 1024 + l * 16);
            u1[nt] = __builtin_amdgcn_mfma_f32_16x16x32_bf16(wB0, hB0, u1[nt], 0, 0, 0);
            u1[nt] = __builtin_amdgcn_mfma_f32_16x16x32_bf16(wB1, hB1, u1[nt], 0, 0, 0);
        }
        float S = 0.f, Q2 = 0.f;
        #pragma unroll
        for (int nt = 0; nt < 16; ++nt) {
            float4 bv = *(const float4*)(c2b2 + nt * 16 + lg * 4);
            u1[nt][0] += bv.x; u1[nt][1] += bv.y; u1[nt][2] += bv.z; u1[nt][3] += bv.w;
            S  += u1[nt][0] + u1[nt][1] + u1[nt][2] + u1[nt][3];
            Q2 += u1[nt][0] * u1[nt][0] + u1[nt][1] * u1[nt][1]
                + u1[nt][2] * u1[nt][2] + u1[nt][3] * u1[nt][3];
        }
        S  += __shfl_xor(S, 16);  S  += __shfl_xor(S, 32);
        Q2 += __shfl_xor(Q2, 16); Q2 += __shfl_xor(Q2, 32);
        float mu  = S * (1.f / 256.f);
        float rsg = rsqrtf(Q2 * (1.f / 256.f) - mu * mu + 1e-6f);
        #pragma unroll
        for (int nt = 0; nt < 16; ++nt) {
            float4 gv  = *(const float4*)(c2g  + nt * 16 + lg * 4);
            float4 bev = *(const float4*)(c2be + nt * 16 + lg * 4);
            float4 xv  = *(const float4*)(erow + nt * 16 + lg * 4);
            float g4[4] = { gv.x, gv.y, gv.z, gv.w };
            float e4[4] = { bev.x, bev.y, bev.z, bev.w };
            float x4[4] = { xv.x, xv.y, xv.z, xv.w };
            float pm[4];
            #pragma unroll
            for (int r = 0; r < 4; ++r) {
                float ln = (u1[nt][r] - mu) * rsg * g4[r] + e4[r];
                float sg = 1.f / (1.f + __expf(-ln));
                pm[r] = (float)Ph[nt][r >> 1][r & 1] + 0.5f * sg * x4[r];
            }
            u32x2 wv;
            wv[0] = pk2(pm[0], pm[1]); wv[1] = pk2(pm[2], pm[3]);
            *(u32x2*)(hb + lr * 512 + ((nt * 32 + lg * 8) ^ swz)) = wv;
        }
        // qf frags (kept in regs through gate + epilogue)
        #pragma unroll
        for (int ks = 0; ks < 8; ++ks) {
            int k0 = ks * 32 + lg * 8;
            float4 q0v = *(const float4*)(qrow + k0), q1v = *(const float4*)(qrow + k0 + 4);
            u32x4 a;
            a[0] = pk2(q0v.x, q0v.y); a[1] = pk2(q0v.z, q0v.w);
            a[2] = pk2(q1v.x, q1v.y); a[3] = pk2(q1v.z, q1v.w);
            qff[ks] = __builtin_bit_cast(bf16x8, a);
        }
        asm volatile("s_waitcnt lgkmcnt(0)" ::: "memory");
    }
    // pooled frags (read once; sP untouched for rest of kernel)
    bf16x8 xfp[8];
    #pragma unroll
    for (int ks = 0; ks < 8; ++ks)
        xfp[ks] = *(const bf16x8*)(hb + lr * 512 + ((ks * 64 + lg * 16) ^ swz));
    __syncthreads();
    stage_chunk(wsb, 5, sW[1], wid, l);

    // ---------- gate chunks 4..11 (cc = 0..7): GEMM + logit fold ----------
    float t0 = 0.f, t1 = 0.f;
    #pragma unroll
    for (int cc = 0; cc < 8; ++cc) {
        const char* wb = (const char*)sW[cc & 1];
        f32x4 ga0 = {}, ga1 = {};
        #pragma unroll
        for (int kk = 0; kk < 16; ++kk) {
            bf16x8 xk = (kk < 8) ? xfp[kk] : qff[kk - 8];
            bf16x8 wA = *(const bf16x8*)(wb + kk * 1024 + l * 16);
            bf16x8 wB = *(const bf16x8*)(wb + (16 + kk) * 1024 + l * 16);
            ga0 = __builtin_amdgcn_mfma_f32_16x16x32_bf16(wA, xk, ga0, 0, 0, 0);
            ga1 = __builtin_amdgcn_mfma_f32_16x16x32_bf16(wB, xk, ga1, 0, 0, 0);
        }
        #pragma unroll
        for (int t2 = 0; t2 < 2; ++t2) {
            f32x4 ga = t2 ? ga1 : ga0;
            int nt = cc * 2 + t2;
            float4 gbv = *(const float4*)(gb1 + nt * 16 + lg * 4);
            float4 w0v = *(const float4*)(gw2 + nt * 16 + lg * 4);
            float4 w1v = *(const float4*)(gw2 + 256 + nt * 16 + lg * 4);
            float gb4[4] = { gbv.x, gbv.y, gbv.z, gbv.w };
            float w04[4] = { w0v.x, w0v.y, w0v.z, w0v.w };
            float w14[4] = { w1v.x, w1v.y, w1v.z, w1v.w };
            #pragma unroll
            for (int r = 0; r < 4; ++r) {
                float hv = fmaxf(ga[r] + gb4[r], 0.f);
                t0 += hv * w04[r]; t1 += hv * w14[r];
            }
        }
        __syncthreads();
        if (cc < 6) stage_chunk(wsb, 6 + cc, sW[cc & 1], wid, l);
    }

    // ---------- logits + softmax(2) + store ----------
    t0 += __shfl_xor(t0, 16); t0 += __shfl_xor(t0, 32);
    t1 += __shfl_xor(t1, 16); t1 += __shfl_xor(t1, 32);
    float g0 = 1.f / (1.f + __expf((t1 + gb2[1]) - (t0 + gb2[0])));
    float g1v = 1.f - g0;

    float* orow = out + (size_t)(rowb + lr) * C;
    #pragma unroll
    for (int ks = 0; ks < 8; ++ks) {
        u32x4 pu = __builtin_bit_cast(u32x4, xfp[ks]);
        u32x4 qu = __builtin_bit_cast(u32x4, qff[ks]);
        float4 o0, o1;
        o0.x = bflo(pu[0]) * g0 + bflo(qu[0]) * g1v;
        o0.y = bfhi(pu[0]) * g0 + bfhi(qu[0]) * g1v;
        o0.z = bflo(pu[1]) * g0 + bflo(qu[1]) * g1v;
        o0.w = bfhi(pu[1]) * g0 + bfhi(qu[1]) * g1v;
        o1.x = bflo(pu[2]) * g0 + bflo(qu[2]) * g1v;
        o1.y = bfhi(pu[2]) * g0 + bfhi(qu[2]) * g1v;
        o1.z = bflo(pu[3]) * g0 + bflo(qu[3]) * g1v;
        o1.w = bfhi(pu[3]) * g0 + bfhi(qu[3]) * g1v;
        *(float4*)(orow + ks * 32 + lg * 8)     = o0;
        *(float4*)(orow + ks * 32 + lg * 8 + 4) = o1;
    }
}

extern "C" void kernel_launch(void* const* d_in, const int* in_sizes, int n_in,
                              void* d_out, int out_size, void* d_ws, size_t ws_size,
                              hipStream_t stream) {
    const float* feat  = (const float*)d_in[0];
    const float* qbox  = (const float*)d_in[1];
    const float* qfeat = (const float*)d_in[2];
    const float* posf  = (const float*)d_in[3];
    const float* c1w1  = (const float*)d_in[4];
    const float* c1b1  = (const float*)d_in[5];
    const float* c1w2  = (const float*)d_in[6];
    const float* c1b2  = (const float*)d_in[7];
    const float* c1g   = (const float*)d_in[8];
    const float* c1be  = (const float*)d_in[9];
    const float* c2w1  = (const float*)d_in[10];
    const float* c2b1  = (const float*)d_in[11];
    const float* c2w2  = (const float*)d_in[12];
    const float* c2b2  = (const float*)d_in[13];
    const float* c2g   = (const float*)d_in[14];
    const float* c2be  = (const float*)d_in[15];
    const float* gw1   = (const float*)d_in[16];
    const float* gb1   = (const float*)d_in[17];
    const float* gw2   = (const float*)d_in[18];
    const float* gb2   = (const float*)d_in[19];
    float* out = (float*)d_out;
    unsigned short* wsb = (unsigned short*)d_ws;   // 393216 B used

    prep_weights<<<96, 256, 0, stream>>>(c1w1, c2w1, c1w2, c2w2, gw1, wsb);

    dim3 grid((NB * NQ) / 32), block(128);         // 2048 blocks, 2 waves, 16 rows/wave
    semalign_v7<<<grid, block, 0, stream>>>(
        feat, qbox, qfeat, posf,
        c1b1, c1b2, c1g, c1be,
        c2b1, c2b2, c2g, c2be,
        gb1, gw2, gb2, wsb, out);
}